// Round 1
// baseline (95.371 us; speedup 1.0000x reference)
//
#include <hip/hip_runtime.h>
#include <hip/hip_cooperative_groups.h>

namespace cg = cooperative_groups;

// HardNegativeContrastiveLoss, B=8192, D=128, T=0.1, margin=0.5.
//
// Analytic collapse: the reference masks only the (i,B+i)/(B+i,i) pairs in
// neg_sim — NOT the diagonal. After row-normalization the diagonal entry is
// ||z_norm||^2 == 1, the maximum possible cosine similarity, so
// hardest_neg[row] is always the diagonal self-sim / T. The 16384^2 matmul
// collapses to three per-row dot products:
//   loss = mean over 2B rows of relu(self_sim/T + margin - pos_sim)
//
// R3: dur_us is dominated by the harness's 256 MB d_ws re-poison
// (~42 us fillBuffer, itself at ~80% HBM peak) + input restores;
// controllable share ~13 us. This round removes one graph node by fusing
// partial+final into a single cooperative kernel (grid.sync between the
// partial phase and the block-0 final reduction). 256 blocks = 1 block/CU
// guarantees co-residency for the cooperative launch; 8 float4 loads are
// issued up-front per lane (128 B in flight) so 4 waves/CU still saturates
// the per-CU HBM share.

constexpr int   kB       = 8192;
constexpr int   kD       = 128;
constexpr float kInvT    = 10.0f;     // 1 / 0.1
constexpr float kMargin  = 0.5f;
constexpr int   kBlocks  = 256;       // 1 block/CU — cooperative co-residency safe
constexpr int   kThreads = 256;       // 4 waves/block
constexpr int   kIters   = 4;         // 256 blk * 4 waves * 2 rows * 4 iters = 8192 row-pairs

__global__ __launch_bounds__(kThreads) void hncl_fused(const float* __restrict__ z1,
                                                       const float* __restrict__ z2,
                                                       float* __restrict__ ws,
                                                       float* __restrict__ out) {
    const int lane        = threadIdx.x & 63;
    const int sub         = lane & 31;    // lane within 32-lane half
    const int half        = lane >> 5;    // which row of the wave's pair
    const int wave_in_blk = threadIdx.x >> 6;               // 0..3
    const int gwave       = blockIdx.x * 4 + wave_in_blk;   // 0..1023

    // Issue all loads before any reduction: 8 x float4 = 128 B/lane in flight.
    // Each 32-lane half reads one contiguous 512 B row; the wave reads 1 KB.
    float4 a[kIters], b[kIters];
    #pragma unroll
    for (int it = 0; it < kIters; ++it) {
        const int row = gwave * 2 + half + it * (kB / kIters);
        a[it] = reinterpret_cast<const float4*>(z1 + (size_t)row * kD)[sub];
        b[it] = reinterpret_cast<const float4*>(z2 + (size_t)row * kD)[sub];
    }

    float local = 0.0f;
    #pragma unroll
    for (int it = 0; it < kIters; ++it) {
        float d11 = a[it].x * a[it].x + a[it].y * a[it].y + a[it].z * a[it].z + a[it].w * a[it].w;
        float d22 = b[it].x * b[it].x + b[it].y * b[it].y + b[it].z * b[it].z + b[it].w * b[it].w;
        float d12 = a[it].x * b[it].x + a[it].y * b[it].y + a[it].z * b[it].z + a[it].w * b[it].w;

        // reduce within the 32-lane half
        #pragma unroll
        for (int off = 16; off > 0; off >>= 1) {
            d11 += __shfl_down(d11, off, 32);
            d22 += __shfl_down(d22, off, 32);
            d12 += __shfl_down(d12, off, 32);
        }

        if (sub == 0) {
            const float n1 = fmaxf(sqrtf(d11), 1e-12f);
            const float n2 = fmaxf(sqrtf(d22), 1e-12f);
            const float pos = d12 / (n1 * n2);
            const float s1  = d11 / (n1 * n1);   // == 1 up to rounding
            const float s2  = d22 / (n2 * n2);
            local += fmaxf(s1 * kInvT + kMargin - pos, 0.0f)
                   + fmaxf(s2 * kInvT + kMargin - pos, 0.0f);
        }
    }

    __shared__ float wsum[8];
    if (sub == 0) wsum[wave_in_blk * 2 + half] = local;
    __syncthreads();
    if (threadIdx.x == 0) {
        float s = 0.0f;
        #pragma unroll
        for (int i = 0; i < 8; ++i) s += wsum[i];
        ws[blockIdx.x] = s;   // plain store — overwrites poison, no atomics
    }

    // One partial per block is now in ws[0..255]. Grid-wide sync (includes the
    // device-scope fence needed for cross-XCD visibility), then block 0 reduces.
    cg::this_grid().sync();

    if (blockIdx.x == 0) {
        float v = ws[threadIdx.x];               // kBlocks == kThreads
        #pragma unroll
        for (int off = 32; off > 0; off >>= 1) v += __shfl_down(v, off, 64);

        __shared__ float fsum[4];
        if (lane == 0) fsum[wave_in_blk] = v;
        __syncthreads();
        if (threadIdx.x == 0) {
            out[0] = (fsum[0] + fsum[1] + fsum[2] + fsum[3]) * (1.0f / (2.0f * (float)kB));
        }
    }
}

extern "C" void kernel_launch(void* const* d_in, const int* in_sizes, int n_in,
                              void* d_out, int out_size, void* d_ws, size_t ws_size,
                              hipStream_t stream) {
    const float* z1 = reinterpret_cast<const float*>(d_in[0]);
    const float* z2 = reinterpret_cast<const float*>(d_in[1]);
    float* ws  = reinterpret_cast<float*>(d_ws);
    float* out = reinterpret_cast<float*>(d_out);

    void* args[] = {(void*)&z1, (void*)&z2, (void*)&ws, (void*)&out};
    hipLaunchCooperativeKernel(reinterpret_cast<const void*>(hncl_fused),
                               dim3(kBlocks), dim3(kThreads), args, 0, stream);
}

// Round 2
// 59.920 us; speedup vs baseline: 1.5916x; 1.5916x over previous
//
#include <hip/hip_runtime.h>

// HardNegativeContrastiveLoss, B=8192, D=128, T=0.1, margin=0.5.
//
// Analytic collapse: the reference masks only the (i,B+i)/(B+i,i) pairs in
// neg_sim — NOT the diagonal. After row-normalization the diagonal entry is
// ||z_norm||^2 == 1, the maximum possible cosine similarity, so
// hardest_neg[row] is always the diagonal self-sim / T. The 16384^2 matmul
// collapses to three per-row dot products:
//   loss = mean over 2B rows of relu(self_sim/T + margin - pos_sim)
//
// R4: REVERT to the R2 two-kernel structure (59.9 us, absmax 0.0).
// R3's cooperative-launch fusion regressed +35 us — hipLaunchCooperativeKernel
// under this harness's graph capture serializes / the grid.sync spin-wait
// costs far more than the removed ~3 us graph node. Do not retry coop launch.
//
// Cost accounting at 59.9 us: ~42 us harness d_ws re-poison (256 MB fill,
// itself at ~81% HBM peak), ~2.5 us input restores, ~1.3 us mandatory 8 MB
// read in k1, ~2 us k2, rest launch gaps. Controllable share is
// launch-overhead-dominated; this structure is at the practical floor.

constexpr int   kB      = 8192;
constexpr int   kD      = 128;
constexpr float kInvT   = 10.0f;     // 1 / 0.1
constexpr float kMargin = 0.5f;
constexpr int   kBlocks = 512;       // k1 grid; d_ws holds kBlocks floats

__global__ __launch_bounds__(256) void hncl_partial(const float* __restrict__ z1,
                                                    const float* __restrict__ z2,
                                                    float* __restrict__ ws) {
    const int lane        = threadIdx.x & 63;
    const int sub         = lane & 31;    // lane within 32-lane half
    const int half        = lane >> 5;    // which row of the wave's pair
    const int wave_in_blk = threadIdx.x >> 6;               // 0..3
    const int gwave       = blockIdx.x * 4 + wave_in_blk;   // 0..2047

    float local = 0.0f;

    // Each wave covers 2 rows/iter (32 lanes x float4 = 128 floats = 1 row).
    // Adjacent rows are contiguous, so the full wave reads 1 KB contiguous.
    #pragma unroll
    for (int iter = 0; iter < 2; ++iter) {
        const int row = gwave * 2 + half + iter * (kB / 2);
        const float4 a = reinterpret_cast<const float4*>(z1 + (size_t)row * kD)[sub];
        const float4 b = reinterpret_cast<const float4*>(z2 + (size_t)row * kD)[sub];

        float d11 = a.x * a.x + a.y * a.y + a.z * a.z + a.w * a.w;
        float d22 = b.x * b.x + b.y * b.y + b.z * b.z + b.w * b.w;
        float d12 = a.x * b.x + a.y * b.y + a.z * b.z + a.w * b.w;

        // reduce within the 32-lane half
        #pragma unroll
        for (int off = 16; off > 0; off >>= 1) {
            d11 += __shfl_down(d11, off, 32);
            d22 += __shfl_down(d22, off, 32);
            d12 += __shfl_down(d12, off, 32);
        }

        if (sub == 0) {
            const float n1 = fmaxf(sqrtf(d11), 1e-12f);
            const float n2 = fmaxf(sqrtf(d22), 1e-12f);
            const float pos = d12 / (n1 * n2);
            const float s1  = d11 / (n1 * n1);   // == 1 up to rounding
            const float s2  = d22 / (n2 * n2);
            local += fmaxf(s1 * kInvT + kMargin - pos, 0.0f)
                   + fmaxf(s2 * kInvT + kMargin - pos, 0.0f);
        }
    }

    __shared__ float wsum[8];
    if (sub == 0) wsum[wave_in_blk * 2 + half] = local;
    __syncthreads();
    if (threadIdx.x == 0) {
        float s = 0.0f;
        #pragma unroll
        for (int i = 0; i < 8; ++i) s += wsum[i];
        ws[blockIdx.x] = s;   // plain store — overwrites poison, no atomics
    }
}

__global__ __launch_bounds__(256) void hncl_final(const float* __restrict__ ws,
                                                  float* __restrict__ out) {
    const int lane = threadIdx.x & 63;
    const int wave = threadIdx.x >> 6;           // 4 waves

    const float2 p = reinterpret_cast<const float2*>(ws)[threadIdx.x];
    float v = p.x + p.y;                         // 512 partials, 2 per thread
    #pragma unroll
    for (int off = 32; off > 0; off >>= 1) v += __shfl_down(v, off, 64);

    __shared__ float wsum[4];
    if (lane == 0) wsum[wave] = v;
    __syncthreads();
    if (threadIdx.x == 0) {
        out[0] = (wsum[0] + wsum[1] + wsum[2] + wsum[3]) * (1.0f / (2.0f * (float)kB));
    }
}

extern "C" void kernel_launch(void* const* d_in, const int* in_sizes, int n_in,
                              void* d_out, int out_size, void* d_ws, size_t ws_size,
                              hipStream_t stream) {
    const float* z1 = reinterpret_cast<const float*>(d_in[0]);
    const float* z2 = reinterpret_cast<const float*>(d_in[1]);
    float* ws  = reinterpret_cast<float*>(d_ws);
    float* out = reinterpret_cast<float*>(d_out);

    hncl_partial<<<kBlocks, 256, 0, stream>>>(z1, z2, ws);
    hncl_final<<<1, 256, 0, stream>>>(ws, out);
}